// Round 6
// baseline (201.620 us; speedup 1.0000x reference)
//
#include <hip/hip_runtime.h>
#include <stdint.h>

// LinearAttention (literal listing, softmax over n):
//   ctx_h = softmax_n(K_h) @ V_h^T;  out = wout·(ctx^T ⊛ q) + b
//   collapsed: out[b] = Weff[b]@x[b]+b,  Weff = wout·blockdiag(ctx^T)·W_q
// ROUND 16: consolidation of proven parts only.
//  * Round-15 post-mortem: ds_read_b64_tr_b16 has a FIXED internal 4x16
//    subtile mapping (m156/m162), not per-lane strided reads -> my layout
//    delivered permuted B-frags (absmax 6.14). Reverted to the round-0
//    scalar gather (proven bit-exact, 70us kernel).
//  * k1v = round-0 k1p body verbatim (1728 blocks x 4 tiles, XT[2][64][68]
//    dbuf staging, scalar ds_read_u16 gather, VGPR 60 no-spill) with ONE
//    delta: mode-0 flush = plain per-block partial stores (validated in
//    round 3) instead of 7.13M device atomics. Isolates the atomic cost.
//  * k2pre: 128 blocks (round-3's 32 was occupancy-starved), float4 sums.
//  * k2s unchanged. k3c = round-3's proven direct-store kernel (~33us).
//  * Known fixed overhead: harness ws-poison fill = 41us/268MB per iter.

using f32x4 = __attribute__((ext_vector_type(4))) float;
using s16x8 = __attribute__((ext_vector_type(8))) short;

#define NSP 110592  // 48*48*48
#define NSHADOW 16
#define MFMA(a, b, c) __builtin_amdgcn_mfma_f32_16x16x32_bf16((a), (b), (c), 0, 0, 0)

static __device__ __forceinline__ unsigned short f2bf(float f) {
    return (unsigned short)((__float_as_uint(f) + 0x8000u) >> 16);  // round-half-up
}

// ---------------------------------------------------------------------------
// k1v: 1728 blocks (864/batch), 4 contiguous 32-n tiles, software-pipelined
// (dbuf XT, 1 barrier/iter, cross-tile prefetch). Round-0 k1p body.
// mode 0: per-block partial stores to Sp/Zp. mode 1: 16-shadow atomics.
// ---------------------------------------------------------------------------
__global__ __launch_bounds__(256, 4) void k1v(
    const float* __restrict__ x, const float* __restrict__ wqkv,
    float* __restrict__ Sdst, float* __restrict__ Zdst, int mode)
{
    __shared__ unsigned short XT[2][64][68];      // dbuf staged x tile (bf16)
    __shared__ unsigned short EKV[4][2][32][40];  // wave-private [K/V][row][col]
    const int tid = threadIdx.x;
    const int wv = tid >> 6;
    const int l = tid & 63;
    const int l15 = l & 15, l4 = l >> 4;
    const int blk = blockIdx.x;
    const int b = blk / 864;            // 864 blocks/batch
    const int tbase = (blk % 864) * 4;  // 4 contiguous tiles
    const int h = wv;

    // A-frags: rows of W_k (128+h*32+m) / W_v (256+h*32+m); A[m=l15][k=l4*8+j]
    s16x8 afr[2][2][2];  // [kv][mtile][kstep]
    for (int kv = 0; kv < 2; ++kv)
        for (int mt = 0; mt < 2; ++mt)
            for (int s = 0; s < 2; ++s) {
                int row = 128 + kv * 128 + h * 32 + mt * 16 + l15;
                const float* wp = wqkv + row * 64 + s * 32 + l4 * 8;
                s16x8 a;
#pragma unroll
                for (int j = 0; j < 8; ++j) a[j] = (short)f2bf(wp[j]);
                afr[kv][mt][s] = a;
            }

    f32x4 sacc[2][2] = {};
    float zrow[8] = {};

    unsigned short (*EK)[40] = EKV[wv][0];
    unsigned short (*EV)[40] = EKV[wv][1];
    const float* xb = x + (size_t)b * 64 * NSP;

    // staging addresses for this thread (2 float4 per tile)
    const int c0 = tid >> 3;                        // p=0 row
    const int ng0 = (tid & 7) ^ (c0 & 7);
    const int c1 = (tid + 256) >> 3;                // p=1 row
    const int ng1 = ((tid + 256) & 7) ^ (c1 & 7);

    float4 g0, g1;
    {   // preload tile 0
        const int n0 = tbase * 32;
        g0 = *(const float4*)(xb + (size_t)c0 * NSP + n0 + 4 * ng0);
        g1 = *(const float4*)(xb + (size_t)c1 * NSP + n0 + 4 * ng1);
    }

    for (int it = 0; it < 4; ++it) {
        unsigned short (*XB)[68] = XT[it & 1];
        // write staged regs -> XT[buf]
        {
            ushort4 u;
            u.x = f2bf(g0.x); u.y = f2bf(g0.y); u.z = f2bf(g0.z); u.w = f2bf(g0.w);
            *(ushort4*)&XB[c0][4 * ng0] = u;
            u.x = f2bf(g1.x); u.y = f2bf(g1.y); u.z = f2bf(g1.z); u.w = f2bf(g1.w);
            *(ushort4*)&XB[c1][4 * ng1] = u;
        }
        // issue next tile's loads; they fly across the barrier + compute
        if (it < 3) {
            const int n0 = (tbase + it + 1) * 32;
            g0 = *(const float4*)(xb + (size_t)c0 * NSP + n0 + 4 * ng0);
            g1 = *(const float4*)(xb + (size_t)c1 * NSP + n0 + 4 * ng1);
        }
        __syncthreads();

        // GEMM1: [K_h;V_h] = W @ xtile (M=64,K=64,N=32)
        f32x4 ck[2][2] = {}, cv[2][2] = {};
#pragma unroll
        for (int s = 0; s < 2; ++s)
#pragma unroll
            for (int nt = 0; nt < 2; ++nt) {
                s16x8 bfr;  // B[k=c][n]: n=l15, c=l4*8+j (+32s)
#pragma unroll
                for (int j = 0; j < 8; ++j)
                    bfr[j] = (short)XB[s * 32 + l4 * 8 + j][nt * 16 + l15];
#pragma unroll
                for (int mt = 0; mt < 2; ++mt) {
                    ck[mt][nt] = MFMA(afr[0][mt][s], bfr, ck[mt][nt]);
                    cv[mt][nt] = MFMA(afr[1][mt][s], bfr, cv[mt][nt]);
                }
            }
        // exp -> Z(regs) + EK; V -> EV   (C: row=mt*16+l4*4+r, col=nt*16+l15)
#pragma unroll
        for (int mt = 0; mt < 2; ++mt)
#pragma unroll
            for (int nt = 0; nt < 2; ++nt) {
                int col = nt * 16 + l15;
#pragma unroll
                for (int r = 0; r < 4; ++r) {
                    int row = mt * 16 + l4 * 4 + r;
                    float ek = __expf(ck[mt][nt][r]);
                    zrow[mt * 4 + r] += ek;
                    EK[row][col] = f2bf(ek);
                    EV[row][col] = f2bf(cv[mt][nt][r]);
                }
            }
        // GEMM2: S_h += expK(32x32) @ V^T (wave-private, in-order DS pipe)
#pragma unroll
        for (int td = 0; td < 2; ++td) {
            s16x8 a2 = *(const s16x8*)&EK[td * 16 + l15][l4 * 8];
#pragma unroll
            for (int te = 0; te < 2; ++te) {
                s16x8 b2 = *(const s16x8*)&EV[te * 16 + l15][l4 * 8];
                sacc[td][te] = MFMA(a2, b2, sacc[td][te]);
            }
        }
        // no second barrier: next iter writes the other XT buffer
    }

    // Z: butterfly over the 16 replicating l15 lanes
#pragma unroll
    for (int i = 0; i < 8; ++i) {
        float z = zrow[i];
        z += __shfl_xor(z, 1);
        z += __shfl_xor(z, 2);
        z += __shfl_xor(z, 4);
        z += __shfl_xor(z, 8);
        zrow[i] = z;
    }

    if (mode == 0) {
        // per-block partial: plain stores, fully written, no zeroing needed
        float* Zb = Zdst + (size_t)blk * 128;
        if (l15 == 0)
#pragma unroll
            for (int mt = 0; mt < 2; ++mt)
#pragma unroll
                for (int r = 0; r < 4; ++r)
                    Zb[h * 32 + mt * 16 + l4 * 4 + r] = zrow[mt * 4 + r];
        float* Sb = Sdst + (size_t)blk * 4096 + h * 1024;
#pragma unroll
        for (int td = 0; td < 2; ++td)
#pragma unroll
            for (int te = 0; te < 2; ++te)
#pragma unroll
                for (int r = 0; r < 4; ++r)
                    Sb[(td * 16 + l4 * 4 + r) * 32 + te * 16 + l15] =
                        sacc[td][te][r];
    } else {
        const int shadow = blk & (NSHADOW - 1);
        float* Zb = Zdst + (size_t)(shadow * 2 + b) * 128;
        if (l15 == 0)
#pragma unroll
            for (int mt = 0; mt < 2; ++mt)
#pragma unroll
                for (int r = 0; r < 4; ++r)
                    atomicAdd(&Zb[h * 32 + mt * 16 + l4 * 4 + r], zrow[mt * 4 + r]);
        float* Sb = Sdst + (size_t)(shadow * 2 + b) * 4096 + h * 1024;
#pragma unroll
        for (int td = 0; td < 2; ++td)
#pragma unroll
            for (int te = 0; te < 2; ++te)
#pragma unroll
                for (int r = 0; r < 4; ++r)
                    atomicAdd(&Sb[(td * 16 + l4 * 4 + r) * 32 + te * 16 + l15],
                              sacc[td][te][r]);
    }
}

// ---------------------------------------------------------------------------
// k2pre: 128 blocks (16 groups x 2 batches x 4 quarter-rows) x 256 threads:
// sum 54 per-block partials (w = s + 16j) -> 16-intermediate layout for k2s.
// ---------------------------------------------------------------------------
__global__ __launch_bounds__(256) void k2pre(
    const float* __restrict__ Sp, const float* __restrict__ Zp,
    float* __restrict__ Ssh, float* __restrict__ Zsh)
{
    const int q = blockIdx.x & 3;
    const int b = (blockIdx.x >> 2) & 1;
    const int s = blockIdx.x >> 3;
    const int t = threadIdx.x;
    const int i = q * 1024 + t * 4;
    float4 acc = {0.f, 0.f, 0.f, 0.f};
#pragma unroll 6
    for (int j = 0; j < 54; ++j) {
        const float4 v =
            *(const float4*)&Sp[(size_t)(b * 864 + s + 16 * j) * 4096 + i];
        acc.x += v.x; acc.y += v.y; acc.z += v.z; acc.w += v.w;
    }
    *(float4*)&Ssh[(size_t)(s * 2 + b) * 4096 + i] = acc;
    if (q == 0 && t < 128) {
        float z = 0.f;
#pragma unroll 6
        for (int j = 0; j < 54; ++j)
            z += Zp[(size_t)(b * 864 + s + 16 * j) * 128 + t];
        Zsh[(size_t)(s * 2 + b) * 128 + t] = z;
    }
}

// ---------------------------------------------------------------------------
// k2s: sum 16 shadows -> ctx = S/Z; P[c][hd] = sum_e wout[c][h*32+e]*ctx[h][d][e];
//      Weff[c][c2] = sum_hd P[c][hd]*wqkv[hd][c2] -> bf16
// ---------------------------------------------------------------------------
__global__ __launch_bounds__(1024) void k2s(
    const float* __restrict__ Ssh, const float* __restrict__ Zsh,
    const float* __restrict__ wout, const float* __restrict__ wqkv,
    unsigned short* __restrict__ WE)
{
    __shared__ float ctx[4][32][32];
    __shared__ float P[64][128];
    __shared__ float Zl[128];
    const int b = blockIdx.x;
    const int t = threadIdx.x;
    if (t < 128) {
        float z = 0.f;
#pragma unroll
        for (int s = 0; s < NSHADOW; ++s) z += Zsh[(size_t)(s * 2 + b) * 128 + t];
        Zl[t] = z;
    }
    __syncthreads();
    for (int i = t; i < 4096; i += 1024) {
        float sv = 0.f;
#pragma unroll
        for (int s = 0; s < NSHADOW; ++s) sv += Ssh[(size_t)(s * 2 + b) * 4096 + i];
        int h = i >> 10, d = (i >> 5) & 31;
        ctx[h][d][i & 31] = sv / Zl[h * 32 + d];
    }
    __syncthreads();
    for (int i = t; i < 8192; i += 1024) {
        int c = i >> 7, hd = i & 127, h = hd >> 5, d = hd & 31;
        const float* wo = wout + c * 128 + h * 32;
        float acc = 0.f;
#pragma unroll 8
        for (int e = 0; e < 32; ++e) acc += wo[e] * ctx[h][d][e];
        P[c][hd] = acc;
    }
    __syncthreads();
    for (int i = t; i < 4096; i += 1024) {
        int c = i >> 6, c2 = i & 63;
        float acc = 0.f;
#pragma unroll 8
        for (int hd = 0; hd < 128; ++hd) acc += P[c][hd] * wqkv[hd * 64 + c2];
        WE[b * 4096 + c * 64 + c2] = f2bf(acc);
    }
}

// ---------------------------------------------------------------------------
// k3c: out[b] = Weff[b]@x[b] + bias. 1728 blocks x 128-col strips; staged XT
// (16.9KB LDS only -> 8 blk/CU), scalar gather, MFMA, DIRECT global stores
// (4x64B segments per instr) — no OT round-trip, single barrier. (round-3,
// proven passing)
// ---------------------------------------------------------------------------
__global__ __launch_bounds__(256) void k3c(
    const float* __restrict__ x, const unsigned short* __restrict__ WE,
    const float* __restrict__ bout, float* __restrict__ out)
{
    __shared__ unsigned short XT[64][132];
    const int tid = threadIdx.x;
    const int wv = tid >> 6;
    const int l = tid & 63;
    const int l15 = l & 15, l4 = l >> 4;
    const int b = blockIdx.x / 864;
    const int n0 = (blockIdx.x % 864) * 128;

    s16x8 afr[4][2];
#pragma unroll
    for (int mt = 0; mt < 4; ++mt)
#pragma unroll
        for (int s = 0; s < 2; ++s)
            afr[mt][s] = *(const s16x8*)(WE + b * 4096 + (mt * 16 + l15) * 64 + s * 32 + l4 * 8);

    float bias[4][4];
#pragma unroll
    for (int mt = 0; mt < 4; ++mt)
#pragma unroll
        for (int r = 0; r < 4; ++r) bias[mt][r] = bout[mt * 16 + l4 * 4 + r];

    const float* xb = x + (size_t)b * 64 * NSP;
    float* ob = out + (size_t)b * 64 * NSP;

#pragma unroll
    for (int p = 0; p < 8; ++p) {
        int idx = tid + 256 * p;
        int c = idx >> 5, ng = idx & 31;
        float4 v = *(const float4*)(xb + (size_t)c * NSP + n0 + 4 * ng);
        ushort4 u;
        u.x = f2bf(v.x); u.y = f2bf(v.y); u.z = f2bf(v.z); u.w = f2bf(v.w);
        *(ushort4*)&XT[c][4 * ng] = u;
    }
    __syncthreads();

    const int nq = wv * 32;
    f32x4 acc[4][2] = {};
#pragma unroll
    for (int s = 0; s < 2; ++s)
#pragma unroll
        for (int nt = 0; nt < 2; ++nt) {
            s16x8 bfr;
#pragma unroll
            for (int j = 0; j < 8; ++j)
                bfr[j] = (short)XT[s * 32 + l4 * 8 + j][nq + nt * 16 + l15];
#pragma unroll
            for (int mt = 0; mt < 4; ++mt) acc[mt][nt] = MFMA(afr[mt][s], bfr, acc[mt][nt]);
        }

    // direct stores: for fixed (mt,nt,r) the wave writes 4 rows x 16
    // consecutive floats = 4 fully-utilized 64B segments.
#pragma unroll
    for (int mt = 0; mt < 4; ++mt)
#pragma unroll
        for (int nt = 0; nt < 2; ++nt)
#pragma unroll
            for (int r = 0; r < 4; ++r)
                ob[(size_t)(mt * 16 + l4 * 4 + r) * NSP + n0 + nq + nt * 16 + l15] =
                    acc[mt][nt][r] + bias[mt][r];
}

extern "C" void kernel_launch(void* const* d_in, const int* in_sizes, int n_in,
                              void* d_out, int out_size, void* d_ws, size_t ws_size,
                              hipStream_t stream) {
    // Inputs by size (order-proof): x=14155776, w_qkv=24576, w_out=8192, b_out=64.
    const float *x = nullptr, *wqkv = nullptr, *wout = nullptr, *bout = nullptr;
    for (int i = 0; i < n_in; ++i) {
        if (in_sizes[i] == 2 * 64 * NSP) x = (const float*)d_in[i];
        else if (in_sizes[i] == 384 * 64) wqkv = (const float*)d_in[i];
        else if (in_sizes[i] == 64 * 128) wout = (const float*)d_in[i];
        else if (in_sizes[i] == 64) bout = (const float*)d_in[i];
    }
    if (!x) x = (const float*)d_in[0];
    if (!wqkv) wqkv = (const float*)d_in[1];
    if (!wout) wout = (const float*)d_in[2];
    if (!bout) bout = (const float*)d_in[3];
    float* out = (float*)d_out;

    // big path layout:
    //   Sp fp32[1728][4096] @0                (28311552 B)
    //   Zp fp32[1728][128]  @28311552         (884736 B)
    //   Ssh fp32[16][2][4096] @29196288       (524288 B)
    //   Zsh fp32[16][2][128]  @29720576       (16384 B)
    //   WE bf16[2][4096]      @29736960       (16384 B)   end: 29753344
    // small path (fallback): Ssh @0, Zsh @524288, WE @540672 (atomics)
    const size_t NEED_BIG = 29753344;
    if (ws_size >= NEED_BIG) {
        float* Sp = (float*)d_ws;
        float* Zp = (float*)((char*)d_ws + 28311552);
        float* Ssh = (float*)((char*)d_ws + 29196288);
        float* Zsh = (float*)((char*)d_ws + 29720576);
        unsigned short* WE = (unsigned short*)((char*)d_ws + 29736960);
        hipLaunchKernelGGL(k1v, dim3(1728), dim3(256), 0, stream, x, wqkv, Sp, Zp, 0);
        hipLaunchKernelGGL(k2pre, dim3(128), dim3(256), 0, stream, Sp, Zp, Ssh, Zsh);
        hipLaunchKernelGGL(k2s, dim3(2), dim3(1024), 0, stream, Ssh, Zsh, wout, wqkv, WE);
        hipLaunchKernelGGL(k3c, dim3(1728), dim3(256), 0, stream, x, WE, bout, out);
    } else {
        float* Ssh = (float*)d_ws;
        float* Zsh = (float*)((char*)d_ws + 524288);
        unsigned short* WE = (unsigned short*)((char*)d_ws + 540672);
        hipMemsetAsync(d_ws, 0, 540672, stream);  // zero shadows
        hipLaunchKernelGGL(k1v, dim3(1728), dim3(256), 0, stream, x, wqkv, Ssh, Zsh, 1);
        hipLaunchKernelGGL(k2s, dim3(2), dim3(1024), 0, stream, Ssh, Zsh, wout, wqkv, WE);
        hipLaunchKernelGGL(k3c, dim3(1728), dim3(256), 0, stream, x, WE, bout, out);
    }
}

// Round 7
// 175.360 us; speedup vs baseline: 1.1497x; 1.1497x over previous
//
#include <hip/hip_runtime.h>
#include <stdint.h>

// LinearAttention (literal listing, softmax over n):
//   ctx_h = softmax_n(K_h) @ V_h^T;  out = wout·(ctx^T ⊛ q) + b
//   collapsed: out[b] = Weff[b]@x[b]+b,  Weff = wout·blockdiag(ctx^T)·W_q
// ROUND 17:
//  * R6 post-mortem: k1v(1728x4,stores)=52us with WRITE 64.8MB (2.2x ideal:
//    write-allocate churn, 1728x16KB partials ~ L2 capacity). KEY: in R3's
//    profile k1u(864x8,stores) never cracked the 41.5us top-5 floor -> the
//    864x8+store config is FASTER (half the partials, half the churn). My
//    "1728>864" rule came from confounded rounds (spill/transpose). Revert.
//  * k1w = round-0 body, 864 blocks x 8 tiles, plain-store flush (= R3 k1u).
//  * k3e: LDS-FREE k3. Unlike k1 (4 waves share one tile -> global gather
//    was 4x redundant, R1 disaster), k3's waves read DISJOINT 32-col slabs:
//    B-frags straight from global (4x64B segments/instr, x read once/block),
//    f2bf in regs, MFMA, direct stores. No LDS, no barrier.
//  * k2pre: 128 blocks, 27 summands (864 partials). k2s unchanged.
//  * Fixed harness overhead (poison fill etc) ~ 85-95us of dur_us.

using f32x4 = __attribute__((ext_vector_type(4))) float;
using s16x8 = __attribute__((ext_vector_type(8))) short;

#define NSP 110592  // 48*48*48
#define NSHADOW 16
#define MFMA(a, b, c) __builtin_amdgcn_mfma_f32_16x16x32_bf16((a), (b), (c), 0, 0, 0)

static __device__ __forceinline__ unsigned short f2bf(float f) {
    return (unsigned short)((__float_as_uint(f) + 0x8000u) >> 16);  // round-half-up
}

// ---------------------------------------------------------------------------
// k1w: 864 blocks (432/batch), 8 contiguous 32-n tiles, software-pipelined
// (dbuf XT, 1 barrier/iter, cross-tile prefetch). Round-0 k1p body.
// mode 0: per-block partial stores to Sp/Zp. mode 1: 16-shadow atomics.
// ---------------------------------------------------------------------------
__global__ __launch_bounds__(256, 4) void k1w(
    const float* __restrict__ x, const float* __restrict__ wqkv,
    float* __restrict__ Sdst, float* __restrict__ Zdst, int mode)
{
    __shared__ unsigned short XT[2][64][68];      // dbuf staged x tile (bf16)
    __shared__ unsigned short EKV[4][2][32][40];  // wave-private [K/V][row][col]
    const int tid = threadIdx.x;
    const int wv = tid >> 6;
    const int l = tid & 63;
    const int l15 = l & 15, l4 = l >> 4;
    const int blk = blockIdx.x;
    const int b = blk / 432;            // 432 blocks/batch
    const int tbase = (blk % 432) * 8;  // 8 contiguous tiles
    const int h = wv;

    // A-frags: rows of W_k (128+h*32+m) / W_v (256+h*32+m); A[m=l15][k=l4*8+j]
    s16x8 afr[2][2][2];  // [kv][mtile][kstep]
    for (int kv = 0; kv < 2; ++kv)
        for (int mt = 0; mt < 2; ++mt)
            for (int s = 0; s < 2; ++s) {
                int row = 128 + kv * 128 + h * 32 + mt * 16 + l15;
                const float* wp = wqkv + row * 64 + s * 32 + l4 * 8;
                s16x8 a;
#pragma unroll
                for (int j = 0; j < 8; ++j) a[j] = (short)f2bf(wp[j]);
                afr[kv][mt][s] = a;
            }

    f32x4 sacc[2][2] = {};
    float zrow[8] = {};

    unsigned short (*EK)[40] = EKV[wv][0];
    unsigned short (*EV)[40] = EKV[wv][1];
    const float* xb = x + (size_t)b * 64 * NSP;

    // staging addresses for this thread (2 float4 per tile)
    const int c0 = tid >> 3;                        // p=0 row
    const int ng0 = (tid & 7) ^ (c0 & 7);
    const int c1 = (tid + 256) >> 3;                // p=1 row
    const int ng1 = ((tid + 256) & 7) ^ (c1 & 7);

    float4 g0, g1;
    {   // preload tile 0
        const int n0 = tbase * 32;
        g0 = *(const float4*)(xb + (size_t)c0 * NSP + n0 + 4 * ng0);
        g1 = *(const float4*)(xb + (size_t)c1 * NSP + n0 + 4 * ng1);
    }

    for (int it = 0; it < 8; ++it) {
        unsigned short (*XB)[68] = XT[it & 1];
        // write staged regs -> XT[buf]
        {
            ushort4 u;
            u.x = f2bf(g0.x); u.y = f2bf(g0.y); u.z = f2bf(g0.z); u.w = f2bf(g0.w);
            *(ushort4*)&XB[c0][4 * ng0] = u;
            u.x = f2bf(g1.x); u.y = f2bf(g1.y); u.z = f2bf(g1.z); u.w = f2bf(g1.w);
            *(ushort4*)&XB[c1][4 * ng1] = u;
        }
        // issue next tile's loads; they fly across the barrier + compute
        if (it < 7) {
            const int n0 = (tbase + it + 1) * 32;
            g0 = *(const float4*)(xb + (size_t)c0 * NSP + n0 + 4 * ng0);
            g1 = *(const float4*)(xb + (size_t)c1 * NSP + n0 + 4 * ng1);
        }
        __syncthreads();

        // GEMM1: [K_h;V_h] = W @ xtile (M=64,K=64,N=32)
        f32x4 ck[2][2] = {}, cv[2][2] = {};
#pragma unroll
        for (int s = 0; s < 2; ++s)
#pragma unroll
            for (int nt = 0; nt < 2; ++nt) {
                s16x8 bfr;  // B[k=c][n]: n=l15, c=l4*8+j (+32s)
#pragma unroll
                for (int j = 0; j < 8; ++j)
                    bfr[j] = (short)XB[s * 32 + l4 * 8 + j][nt * 16 + l15];
#pragma unroll
                for (int mt = 0; mt < 2; ++mt) {
                    ck[mt][nt] = MFMA(afr[0][mt][s], bfr, ck[mt][nt]);
                    cv[mt][nt] = MFMA(afr[1][mt][s], bfr, cv[mt][nt]);
                }
            }
        // exp -> Z(regs) + EK; V -> EV   (C: row=mt*16+l4*4+r, col=nt*16+l15)
#pragma unroll
        for (int mt = 0; mt < 2; ++mt)
#pragma unroll
            for (int nt = 0; nt < 2; ++nt) {
                int col = nt * 16 + l15;
#pragma unroll
                for (int r = 0; r < 4; ++r) {
                    int row = mt * 16 + l4 * 4 + r;
                    float ek = __expf(ck[mt][nt][r]);
                    zrow[mt * 4 + r] += ek;
                    EK[row][col] = f2bf(ek);
                    EV[row][col] = f2bf(cv[mt][nt][r]);
                }
            }
        // GEMM2: S_h += expK(32x32) @ V^T (wave-private, in-order DS pipe)
#pragma unroll
        for (int td = 0; td < 2; ++td) {
            s16x8 a2 = *(const s16x8*)&EK[td * 16 + l15][l4 * 8];
#pragma unroll
            for (int te = 0; te < 2; ++te) {
                s16x8 b2 = *(const s16x8*)&EV[te * 16 + l15][l4 * 8];
                sacc[td][te] = MFMA(a2, b2, sacc[td][te]);
            }
        }
        // no second barrier: next iter writes the other XT buffer
    }

    // Z: butterfly over the 16 replicating l15 lanes
#pragma unroll
    for (int i = 0; i < 8; ++i) {
        float z = zrow[i];
        z += __shfl_xor(z, 1);
        z += __shfl_xor(z, 2);
        z += __shfl_xor(z, 4);
        z += __shfl_xor(z, 8);
        zrow[i] = z;
    }

    if (mode == 0) {
        // per-block partial: plain stores, fully written, no zeroing needed
        float* Zb = Zdst + (size_t)blk * 128;
        if (l15 == 0)
#pragma unroll
            for (int mt = 0; mt < 2; ++mt)
#pragma unroll
                for (int r = 0; r < 4; ++r)
                    Zb[h * 32 + mt * 16 + l4 * 4 + r] = zrow[mt * 4 + r];
        float* Sb = Sdst + (size_t)blk * 4096 + h * 1024;
#pragma unroll
        for (int td = 0; td < 2; ++td)
#pragma unroll
            for (int te = 0; te < 2; ++te)
#pragma unroll
                for (int r = 0; r < 4; ++r)
                    Sb[(td * 16 + l4 * 4 + r) * 32 + te * 16 + l15] =
                        sacc[td][te][r];
    } else {
        const int shadow = blk & (NSHADOW - 1);
        float* Zb = Zdst + (size_t)(shadow * 2 + b) * 128;
        if (l15 == 0)
#pragma unroll
            for (int mt = 0; mt < 2; ++mt)
#pragma unroll
                for (int r = 0; r < 4; ++r)
                    atomicAdd(&Zb[h * 32 + mt * 16 + l4 * 4 + r], zrow[mt * 4 + r]);
        float* Sb = Sdst + (size_t)(shadow * 2 + b) * 4096 + h * 1024;
#pragma unroll
        for (int td = 0; td < 2; ++td)
#pragma unroll
            for (int te = 0; te < 2; ++te)
#pragma unroll
                for (int r = 0; r < 4; ++r)
                    atomicAdd(&Sb[(td * 16 + l4 * 4 + r) * 32 + te * 16 + l15],
                              sacc[td][te][r]);
    }
}

// ---------------------------------------------------------------------------
// k2pre: 128 blocks (16 groups x 2 batches x 4 quarter-rows) x 256 threads:
// sum 27 per-block partials (w = s + 16j) -> 16-intermediate layout for k2s.
// ---------------------------------------------------------------------------
__global__ __launch_bounds__(256) void k2pre(
    const float* __restrict__ Sp, const float* __restrict__ Zp,
    float* __restrict__ Ssh, float* __restrict__ Zsh)
{
    const int q = blockIdx.x & 3;
    const int b = (blockIdx.x >> 2) & 1;
    const int s = blockIdx.x >> 3;
    const int t = threadIdx.x;
    const int i = q * 1024 + t * 4;
    float4 acc = {0.f, 0.f, 0.f, 0.f};
#pragma unroll
    for (int j = 0; j < 27; ++j) {
        const float4 v =
            *(const float4*)&Sp[(size_t)(b * 432 + s + 16 * j) * 4096 + i];
        acc.x += v.x; acc.y += v.y; acc.z += v.z; acc.w += v.w;
    }
    *(float4*)&Ssh[(size_t)(s * 2 + b) * 4096 + i] = acc;
    if (q == 0 && t < 128) {
        float z = 0.f;
#pragma unroll
        for (int j = 0; j < 27; ++j)
            z += Zp[(size_t)(b * 432 + s + 16 * j) * 128 + t];
        Zsh[(size_t)(s * 2 + b) * 128 + t] = z;
    }
}

// ---------------------------------------------------------------------------
// k2s: sum 16 shadows -> ctx = S/Z; P[c][hd] = sum_e wout[c][h*32+e]*ctx[h][d][e];
//      Weff[c][c2] = sum_hd P[c][hd]*wqkv[hd][c2] -> bf16
// ---------------------------------------------------------------------------
__global__ __launch_bounds__(1024) void k2s(
    const float* __restrict__ Ssh, const float* __restrict__ Zsh,
    const float* __restrict__ wout, const float* __restrict__ wqkv,
    unsigned short* __restrict__ WE)
{
    __shared__ float ctx[4][32][32];
    __shared__ float P[64][128];
    __shared__ float Zl[128];
    const int b = blockIdx.x;
    const int t = threadIdx.x;
    if (t < 128) {
        float z = 0.f;
#pragma unroll
        for (int s = 0; s < NSHADOW; ++s) z += Zsh[(size_t)(s * 2 + b) * 128 + t];
        Zl[t] = z;
    }
    __syncthreads();
    for (int i = t; i < 4096; i += 1024) {
        float sv = 0.f;
#pragma unroll
        for (int s = 0; s < NSHADOW; ++s) sv += Ssh[(size_t)(s * 2 + b) * 4096 + i];
        int h = i >> 10, d = (i >> 5) & 31;
        ctx[h][d][i & 31] = sv / Zl[h * 32 + d];
    }
    __syncthreads();
    for (int i = t; i < 8192; i += 1024) {
        int c = i >> 7, hd = i & 127, h = hd >> 5, d = hd & 31;
        const float* wo = wout + c * 128 + h * 32;
        float acc = 0.f;
#pragma unroll 8
        for (int e = 0; e < 32; ++e) acc += wo[e] * ctx[h][d][e];
        P[c][hd] = acc;
    }
    __syncthreads();
    for (int i = t; i < 4096; i += 1024) {
        int c = i >> 6, c2 = i & 63;
        float acc = 0.f;
#pragma unroll 8
        for (int hd = 0; hd < 128; ++hd) acc += P[c][hd] * wqkv[hd * 64 + c2];
        WE[b * 4096 + c * 64 + c2] = f2bf(acc);
    }
}

// ---------------------------------------------------------------------------
// k3e: out[b] = Weff[b]@x[b] + bias. 1728 blocks x 128-col strips. LDS-FREE:
// each wave owns a disjoint 32-col slab (nq=wv*32); B-frags gathered straight
// from global (per load: 4 rows x 16 consecutive floats = 4x64B segments,
// x read exactly once per block), f2bf in regs, MFMA, direct global stores.
// No LDS, no barriers.
// ---------------------------------------------------------------------------
__global__ __launch_bounds__(256) void k3e(
    const float* __restrict__ x, const unsigned short* __restrict__ WE,
    const float* __restrict__ bout, float* __restrict__ out)
{
    const int tid = threadIdx.x;
    const int wv = tid >> 6;
    const int l = tid & 63;
    const int l15 = l & 15, l4 = l >> 4;
    const int b = blockIdx.x / 864;
    const int n0 = (blockIdx.x % 864) * 128;

    s16x8 afr[4][2];
#pragma unroll
    for (int mt = 0; mt < 4; ++mt)
#pragma unroll
        for (int s = 0; s < 2; ++s)
            afr[mt][s] = *(const s16x8*)(WE + b * 4096 + (mt * 16 + l15) * 64 + s * 32 + l4 * 8);

    float bias[4][4];
#pragma unroll
    for (int mt = 0; mt < 4; ++mt)
#pragma unroll
        for (int r = 0; r < 4; ++r) bias[mt][r] = bout[mt * 16 + l4 * 4 + r];

    const float* xb = x + (size_t)b * 64 * NSP;
    float* ob = out + (size_t)b * 64 * NSP;

    const int nq = wv * 32;
    // lane's gather base: row l4*8, col n0+nq+l15
    const float* xq = xb + (size_t)(l4 * 8) * NSP + n0 + nq + l15;

    f32x4 acc[4][2] = {};
#pragma unroll
    for (int s = 0; s < 2; ++s) {
        // load 16 floats: rows s*32+l4*8+j, cols {0,16}
        float t0[8], t1[8];
#pragma unroll
        for (int j = 0; j < 8; ++j) {
            const float* p = xq + (size_t)(s * 32 + j) * NSP;
            t0[j] = p[0];
            t1[j] = p[16];
        }
        s16x8 b0, b1;  // B[k=s*32+l4*8+j][n=nt*16+l15]
#pragma unroll
        for (int j = 0; j < 8; ++j) {
            b0[j] = (short)f2bf(t0[j]);
            b1[j] = (short)f2bf(t1[j]);
        }
#pragma unroll
        for (int mt = 0; mt < 4; ++mt) {
            acc[mt][0] = MFMA(afr[mt][s], b0, acc[mt][0]);
            acc[mt][1] = MFMA(afr[mt][s], b1, acc[mt][1]);
        }
    }

    // direct stores: for fixed (mt,nt,r) the wave writes 4 rows x 16
    // consecutive floats = 4 fully-utilized 64B segments.
#pragma unroll
    for (int mt = 0; mt < 4; ++mt)
#pragma unroll
        for (int nt = 0; nt < 2; ++nt)
#pragma unroll
            for (int r = 0; r < 4; ++r)
                ob[(size_t)(mt * 16 + l4 * 4 + r) * NSP + n0 + nq + nt * 16 + l15] =
                    acc[mt][nt][r] + bias[mt][r];
}

extern "C" void kernel_launch(void* const* d_in, const int* in_sizes, int n_in,
                              void* d_out, int out_size, void* d_ws, size_t ws_size,
                              hipStream_t stream) {
    // Inputs by size (order-proof): x=14155776, w_qkv=24576, w_out=8192, b_out=64.
    const float *x = nullptr, *wqkv = nullptr, *wout = nullptr, *bout = nullptr;
    for (int i = 0; i < n_in; ++i) {
        if (in_sizes[i] == 2 * 64 * NSP) x = (const float*)d_in[i];
        else if (in_sizes[i] == 384 * 64) wqkv = (const float*)d_in[i];
        else if (in_sizes[i] == 64 * 128) wout = (const float*)d_in[i];
        else if (in_sizes[i] == 64) bout = (const float*)d_in[i];
    }
    if (!x) x = (const float*)d_in[0];
    if (!wqkv) wqkv = (const float*)d_in[1];
    if (!wout) wout = (const float*)d_in[2];
    if (!bout) bout = (const float*)d_in[3];
    float* out = (float*)d_out;

    // big path layout:
    //   Sp fp32[864][4096]  @0                (14155776 B)
    //   Zp fp32[864][128]   @14155776         (442368 B)
    //   Ssh fp32[16][2][4096] @14598144       (524288 B)
    //   Zsh fp32[16][2][128]  @15122432       (16384 B)
    //   WE bf16[2][4096]      @15138816       (16384 B)   end: 15155200
    // small path (fallback): Ssh @0, Zsh @524288, WE @540672 (atomics)
    const size_t NEED_BIG = 15155200;
    if (ws_size >= NEED_BIG) {
        float* Sp = (float*)d_ws;
        float* Zp = (float*)((char*)d_ws + 14155776);
        float* Ssh = (float*)((char*)d_ws + 14598144);
        float* Zsh = (float*)((char*)d_ws + 15122432);
        unsigned short* WE = (unsigned short*)((char*)d_ws + 15138816);
        hipLaunchKernelGGL(k1w, dim3(864), dim3(256), 0, stream, x, wqkv, Sp, Zp, 0);
        hipLaunchKernelGGL(k2pre, dim3(128), dim3(256), 0, stream, Sp, Zp, Ssh, Zsh);
        hipLaunchKernelGGL(k2s, dim3(2), dim3(1024), 0, stream, Ssh, Zsh, wout, wqkv, WE);
        hipLaunchKernelGGL(k3e, dim3(1728), dim3(256), 0, stream, x, WE, bout, out);
    } else {
        float* Ssh = (float*)d_ws;
        float* Zsh = (float*)((char*)d_ws + 524288);
        unsigned short* WE = (unsigned short*)((char*)d_ws + 540672);
        hipMemsetAsync(d_ws, 0, 540672, stream);  // zero shadows
        hipLaunchKernelGGL(k1w, dim3(864), dim3(256), 0, stream, x, wqkv, Ssh, Zsh, 1);
        hipLaunchKernelGGL(k2s, dim3(2), dim3(1024), 0, stream, Ssh, Zsh, wout, wqkv, WE);
        hipLaunchKernelGGL(k3e, dim3(1728), dim3(256), 0, stream, x, WE, bout, out);
    }
}